// Round 1
// baseline (924.854 us; speedup 1.0000x reference)
//
#include <hip/hip_runtime.h>
#include <cstdint>
#include <cstddef>

// GCNClassifier: 2x AGNNConv(D=320) -> marker weight -> BN+LeakyReLU ->
// softmax @ ref_center -> 2x AGNNConv(D=16) -> row softmax.
// N=50000, E=300000 (incl. self-loops => every dst segment non-empty).

#define D_BIG 320
#define D_SMALL 16

static constexpr unsigned ENC_NEG_INF = 0x007FFFFFu; // encode(-inf)

__device__ __forceinline__ unsigned enc_f(float f) {
    unsigned u = __float_as_uint(f);
    return (u & 0x80000000u) ? ~u : (u | 0x80000000u);
}
__device__ __forceinline__ float dec_f(unsigned u) {
    return (u & 0x80000000u) ? __uint_as_float(u ^ 0x80000000u) : __uint_as_float(~u);
}

__global__ void fill_u32(unsigned* p, unsigned v, int n) {
    int i = blockIdx.x * blockDim.x + threadIdx.x;
    if (i < n) p[i] = v;
}

__global__ void init_seg(unsigned* emax, float* esum, int n) {
    int i = blockIdx.x * blockDim.x + threadIdx.x;
    if (i < n) { emax[i] = ENC_NEG_INF; esum[i] = 0.f; }
}

// ---------------- row norms (wave per row) ----------------
template <int D>
__global__ void row_norms(const float* __restrict__ h, float* __restrict__ norms, int n) {
    int wid  = (blockIdx.x * blockDim.x + threadIdx.x) >> 6;
    int lane = threadIdx.x & 63;
    if (wid >= n) return;
    const float* r = h + (size_t)wid * D;
    float s = 0.f;
    for (int d = lane; d < D; d += 64) { float v = r[d]; s += v * v; }
    for (int m = 32; m >= 1; m >>= 1) s += __shfl_xor(s, m);
    if (lane == 0) norms[wid] = fmaxf(sqrtf(s), 1e-12f);
}

// ---------------- edge scores ----------------
// D=320: one wave per edge (coalesced strided dot); fused segment-max atomic.
__global__ void edge_scores_big(const float* __restrict__ h, const float* __restrict__ norms,
                                const int* __restrict__ src, const int* __restrict__ dst,
                                const float* __restrict__ beta,
                                float* __restrict__ e, unsigned* __restrict__ emax, int nE) {
    int k    = (blockIdx.x * blockDim.x + threadIdx.x) >> 6;
    int lane = threadIdx.x & 63;
    if (k >= nE) return;
    int s = src[k], t = dst[k];
    const float* ps = h + (size_t)s * D_BIG;
    const float* pt = h + (size_t)t * D_BIG;
    float acc = 0.f;
    #pragma unroll
    for (int u = 0; u < D_BIG / 64; u++) {
        int d = lane + 64 * u;
        acc += ps[d] * pt[d];
    }
    for (int m = 32; m >= 1; m >>= 1) acc += __shfl_xor(acc, m);
    if (lane == 0) {
        float sc = beta[0] * acc / (norms[s] * norms[t]);   // temp = 1.0
        e[k] = sc;
        atomicMax(&emax[t], enc_f(sc));
    }
}

// D=16: one thread per edge (two 64B rows, vectorized).
__global__ void edge_scores_small(const float* __restrict__ h, const float* __restrict__ norms,
                                  const int* __restrict__ src, const int* __restrict__ dst,
                                  const float* __restrict__ beta,
                                  float* __restrict__ e, unsigned* __restrict__ emax, int nE) {
    int k = blockIdx.x * blockDim.x + threadIdx.x;
    if (k >= nE) return;
    int s = src[k], t = dst[k];
    const float4* ps = (const float4*)(h + (size_t)s * D_SMALL);
    const float4* pt = (const float4*)(h + (size_t)t * D_SMALL);
    float acc = 0.f;
    #pragma unroll
    for (int q = 0; q < 4; q++) {
        float4 a = ps[q], b = pt[q];
        acc += a.x * b.x + a.y * b.y + a.z * b.z + a.w * b.w;
    }
    float sc = beta[0] * acc / (norms[s] * norms[t]);
    e[k] = sc;
    atomicMax(&emax[t], enc_f(sc));
}

__global__ void exp_sum(const float* __restrict__ e, const int* __restrict__ dst,
                        const unsigned* __restrict__ emax,
                        float* __restrict__ ex, float* __restrict__ esum, int nE) {
    int k = blockIdx.x * blockDim.x + threadIdx.x;
    if (k >= nE) return;
    int t = dst[k];
    float x = expf(e[k] - dec_f(emax[t]));
    ex[k] = x;
    atomicAdd(&esum[t], x);
}

// ---------------- CSR build (dst-major) ----------------
__global__ void count_deg(const int* __restrict__ dst, unsigned* __restrict__ deg, int nE) {
    int k = blockIdx.x * blockDim.x + threadIdx.x;
    if (k < nE) atomicAdd(&deg[dst[k]], 1u);
}

__global__ void prefix_sum(const unsigned* __restrict__ deg, unsigned* __restrict__ rowstart, int n) {
    __shared__ unsigned buf[1024];
    __shared__ unsigned carry;
    if (threadIdx.x == 0) carry = 0u;
    __syncthreads();
    for (int base = 0; base < n; base += 1024) {
        int i = base + (int)threadIdx.x;
        unsigned v = (i < n) ? deg[i] : 0u;
        buf[threadIdx.x] = v;
        __syncthreads();
        for (int off = 1; off < 1024; off <<= 1) {
            unsigned t = (threadIdx.x >= (unsigned)off) ? buf[threadIdx.x - off] : 0u;
            __syncthreads();
            buf[threadIdx.x] += t;
            __syncthreads();
        }
        unsigned incl  = buf[threadIdx.x];
        unsigned cbase = carry;
        if (i < n) rowstart[i] = cbase + incl - v;
        __syncthreads();
        if (threadIdx.x == 0) carry = cbase + buf[1023];
        __syncthreads();
    }
    if (threadIdx.x == 0) rowstart[n] = carry;
}

__global__ void scatter_edges(const int* __restrict__ src, const int* __restrict__ dst,
                              const unsigned* __restrict__ rowstart, unsigned* __restrict__ cursor,
                              int* __restrict__ eid, int* __restrict__ esrc, int nE) {
    int k = blockIdx.x * blockDim.x + threadIdx.x;
    if (k >= nE) return;
    int t = dst[k];
    unsigned pos = rowstart[t] + atomicAdd(&cursor[t], 1u);
    eid[pos]  = k;
    esrc[pos] = src[k];
}

// ---------------- softmax-weighted aggregation (wave per node) ----------------
template <int D, bool SOFTMAX>
__global__ void aggregate(const float* __restrict__ h, const float* __restrict__ ex,
                          const float* __restrict__ esum, const unsigned* __restrict__ rowstart,
                          const int* __restrict__ eid, const int* __restrict__ esrc,
                          float* __restrict__ out, float inv_temp, int n) {
    int i    = (blockIdx.x * blockDim.x + threadIdx.x) >> 6;
    int lane = threadIdx.x & 63;
    if (i >= n) return;
    unsigned r0 = rowstart[i], r1 = rowstart[i + 1];
    float inv = 1.0f / esum[i];
    constexpr int U = (D + 63) / 64;
    float acc[U];
    #pragma unroll
    for (int u = 0; u < U; u++) acc[u] = 0.f;

    for (unsigned base = r0; base < r1; base += 64) {
        unsigned j = base + (unsigned)lane;
        float attn = 0.f; int s = 0;
        if (j < r1) { s = esrc[j]; attn = ex[eid[j]] * inv; }
        unsigned rem = r1 - base;
        int cnt = rem > 64u ? 64 : (int)rem;
        for (int t = 0; t < cnt; t++) {
            float a  = __shfl(attn, t);
            int   ss = __shfl(s, t);
            const float* pr = h + (size_t)ss * D;
            #pragma unroll
            for (int u = 0; u < U; u++) {
                int d = lane + 64 * u;
                if (d < D) acc[u] += a * pr[d];
            }
        }
    }

    if (!SOFTMAX) {
        #pragma unroll
        for (int u = 0; u < U; u++) {
            int d = lane + 64 * u;
            if (d < D) out[(size_t)i * D + d] = acc[u];
        }
    } else {
        // D == 16: row softmax of acc*inv_temp across lanes 0..15
        float v = acc[0] * inv_temp;
        float m = v;
        for (int mm = 8; mm >= 1; mm >>= 1) m = fmaxf(m, __shfl_xor(m, mm));
        float ee = expf(v - m);
        float ssum = ee;
        for (int mm = 8; mm >= 1; mm >>= 1) ssum += __shfl_xor(ssum, mm);
        if (lane < 16) out[(size_t)i * 16 + lane] = ee / ssum;
    }
}

// ---------------- marker weight (in-place) + f_pre ----------------
__global__ void marker_f(float* __restrict__ fea, const float* __restrict__ mw,
                         float* __restrict__ f_pre, int n) {
    int idx = blockIdx.x * blockDim.x + threadIdx.x;  // over n*16
    if (idx >= n * 16) return;
    int i = idx >> 4, c = idx & 15;
    float* row = fea + (size_t)i * D_BIG;
    float s = 0.f;
    #pragma unroll
    for (int m = 0; m < 20; m++) {
        float v = row[m * 16 + c] * mw[m * 16 + c];
        row[m * 16 + c] = v;
        s += v;
    }
    f_pre[idx] = s;
}

// ---------------- BatchNorm stats ----------------
__global__ void bn_reduce(const float* __restrict__ f, float* __restrict__ stats, int n) {
    int c = threadIdx.x & 15;
    int g = threadIdx.x >> 4;   // 16 node-groups per block
    float s = 0.f, s2 = 0.f;
    for (int i = blockIdx.x * 16 + g; i < n; i += gridDim.x * 16) {
        float v = f[(size_t)i * 16 + c];
        s += v; s2 += v * v;
    }
    __shared__ float ls[256], ls2[256];
    ls[threadIdx.x] = s; ls2[threadIdx.x] = s2;
    __syncthreads();
    for (int off = 128; off >= 16; off >>= 1) {
        if ((int)threadIdx.x < off) {
            ls[threadIdx.x]  += ls[threadIdx.x + off];
            ls2[threadIdx.x] += ls2[threadIdx.x + off];
        }
        __syncthreads();
    }
    if (threadIdx.x < 16) {
        atomicAdd(&stats[threadIdx.x], ls[threadIdx.x]);
        atomicAdd(&stats[16 + threadIdx.x], ls2[threadIdx.x]);
    }
}

__global__ void bn_finalize(float* __restrict__ stats, const float* __restrict__ w,
                            const float* __restrict__ b, int n) {
    int c = threadIdx.x;
    if (c < 16) {
        float mean  = stats[c] / (float)n;
        float var   = fmaxf(stats[16 + c] / (float)n - mean * mean, 0.f);
        float scale = w[c] / sqrtf(var + 1e-5f);
        stats[32 + c] = scale;
        stats[48 + c] = b[c] - mean * scale;
    }
}

// ---------------- BN apply + LeakyReLU + softmax(f/T3) @ ref_center ----------------
__global__ void bn_apply_p(float* __restrict__ f, const float* __restrict__ stats,
                           const float* __restrict__ rc, float* __restrict__ p, int n) {
    __shared__ float s_rc[16 * D_BIG];   // 20 KB
    __shared__ float s_sc[16], s_sh[16];
    for (int idx = threadIdx.x; idx < 16 * D_BIG; idx += blockDim.x) s_rc[idx] = rc[idx];
    if (threadIdx.x < 16) { s_sc[threadIdx.x] = stats[32 + threadIdx.x]; s_sh[threadIdx.x] = stats[48 + threadIdx.x]; }
    __syncthreads();

    int wave = (blockIdx.x * blockDim.x + threadIdx.x) >> 6;
    int nw   = (gridDim.x * blockDim.x) >> 6;
    int lane = threadIdx.x & 63;

    for (int i = wave; i < n; i += nw) {
        const float* fr = f + (size_t)i * 16;
        float fv[16];
        float mx = -1e30f;
        #pragma unroll
        for (int c = 0; c < 16; c++) {
            float v = fmaf(fr[c], s_sc[c], s_sh[c]);
            v = (v >= 0.f) ? v : 0.25f * v;           // LeakyReLU(0.25)
            fv[c] = v;
            mx = fmaxf(mx, v);
        }
        if (lane < 16) f[(size_t)i * 16 + lane] = fv[lane];   // lockstep: all loads precede stores

        float sp[16]; float sum = 0.f;
        #pragma unroll
        for (int c = 0; c < 16; c++) { float t = expf((fv[c] - mx) * 10.0f); sp[c] = t; sum += t; }
        float isum = 1.f / sum;

        #pragma unroll
        for (int u = 0; u < 5; u++) {
            int d = lane + 64 * u;
            float acc = 0.f;
            #pragma unroll
            for (int c = 0; c < 16; c++) acc += sp[c] * s_rc[c * D_BIG + d];
            p[(size_t)i * D_BIG + d] = acc * isum;
        }
    }
}

extern "C" void kernel_launch(void* const* d_in, const int* in_sizes, int n_in,
                              void* d_out, int out_size, void* d_ws, size_t ws_size,
                              hipStream_t stream) {
    const float* x    = (const float*)d_in[0];
    const int*   src  = (const int*)d_in[1];
    const int*   dst  = (const int*)d_in[2];
    const float* mw   = (const float*)d_in[3];
    const float* bnw  = (const float*)d_in[4];
    const float* bnb  = (const float*)d_in[5];
    const float* rc   = (const float*)d_in[6];
    const float* beta = (const float*)d_in[7];

    const int n  = in_sizes[0] / D_BIG;   // 50000
    const int nE = in_sizes[1];           // 300000

    float* out     = (float*)d_out;
    float* fea_out = out;                          // N*320
    float* f_out   = out + (size_t)n * D_BIG;      // N*16
    float* p_out   = f_out + (size_t)n * 16;       // N*320
    float* o_out   = p_out + (size_t)n * D_BIG;    // N*16

    // workspace carve (~10 MB)
    char* w = (char*)d_ws;
    auto carve = [&](size_t bytes) { void* r = (void*)w; w += (bytes + 255) & ~(size_t)255; return r; };
    float*    norms    = (float*)carve((size_t)n * 4);
    float*    e        = (float*)carve((size_t)nE * 4);
    float*    ex       = (float*)carve((size_t)nE * 4);
    unsigned* emax     = (unsigned*)carve((size_t)n * 4);
    float*    esum     = (float*)carve((size_t)n * 4);
    unsigned* deg      = (unsigned*)carve((size_t)n * 4);
    unsigned* rowstart = (unsigned*)carve((size_t)(n + 1) * 4);
    unsigned* cursor   = (unsigned*)carve((size_t)n * 4);
    int*      eidb     = (int*)carve((size_t)nE * 4);
    int*      esrc     = (int*)carve((size_t)nE * 4);
    float*    stats    = (float*)carve(64 * 4);
    float*    t16      = (float*)carve((size_t)n * 16 * 4);
    float*    h1       = p_out;  // p region doubles as conv1 output until bn_apply_p

    const int TB = 256;
    auto cdiv = [](int a, int b) { return (a + b - 1) / b; };

    // CSR build (once; reused by all 4 convs)
    fill_u32<<<cdiv(n, TB), TB, 0, stream>>>(deg, 0u, n);
    count_deg<<<cdiv(nE, TB), TB, 0, stream>>>(dst, deg, nE);
    prefix_sum<<<1, 1024, 0, stream>>>(deg, rowstart, n);
    fill_u32<<<cdiv(n, TB), TB, 0, stream>>>(cursor, 0u, n);
    scatter_edges<<<cdiv(nE, TB), TB, 0, stream>>>(src, dst, rowstart, cursor, eidb, esrc, nE);

    auto conv_big = [&](const float* hin, float* hout) {
        row_norms<D_BIG><<<cdiv(n, 4), TB, 0, stream>>>(hin, norms, n);
        init_seg<<<cdiv(n, TB), TB, 0, stream>>>(emax, esum, n);
        edge_scores_big<<<cdiv(nE, 4), TB, 0, stream>>>(hin, norms, src, dst, beta, e, emax, nE);
        exp_sum<<<cdiv(nE, TB), TB, 0, stream>>>(e, dst, emax, ex, esum, nE);
        aggregate<D_BIG, false><<<cdiv(n, 4), TB, 0, stream>>>(hin, ex, esum, rowstart, eidb, esrc, hout, 0.f, n);
    };
    auto conv_small = [&](const float* hin, float* hout, bool smax, float invt) {
        row_norms<D_SMALL><<<cdiv(n, 4), TB, 0, stream>>>(hin, norms, n);
        init_seg<<<cdiv(n, TB), TB, 0, stream>>>(emax, esum, n);
        edge_scores_small<<<cdiv(nE, TB), TB, 0, stream>>>(hin, norms, src, dst, beta, e, emax, nE);
        exp_sum<<<cdiv(nE, TB), TB, 0, stream>>>(e, dst, emax, ex, esum, nE);
        if (smax)
            aggregate<D_SMALL, true><<<cdiv(n, 4), TB, 0, stream>>>(hin, ex, esum, rowstart, eidb, esrc, hout, invt, n);
        else
            aggregate<D_SMALL, false><<<cdiv(n, 4), TB, 0, stream>>>(hin, ex, esum, rowstart, eidb, esrc, hout, 0.f, n);
    };

    conv_big(x, h1);            // conv1 -> h1 (p region)
    conv_big(h1, fea_out);      // conv2 raw -> fea region
    marker_f<<<cdiv(n * 16, TB), TB, 0, stream>>>(fea_out, mw, f_out, n);   // weight in place + f_pre
    fill_u32<<<1, 64, 0, stream>>>((unsigned*)stats, 0u, 64);
    bn_reduce<<<128, TB, 0, stream>>>(f_out, stats, n);
    bn_finalize<<<1, 16, 0, stream>>>(stats, bnw, bnb, n);
    bn_apply_p<<<1024, TB, 0, stream>>>(f_out, stats, rc, p_out, n);        // f in place; p overwrites h1
    conv_small(f_out, t16, false, 0.f);                                     // conv3
    conv_small(t16, o_out, true, 0.2f);                                     // conv4 + softmax(/5)
}

// Round 2
// 719.273 us; speedup vs baseline: 1.2858x; 1.2858x over previous
//
#include <hip/hip_runtime.h>
#include <cstdint>
#include <cstddef>

// GCNClassifier: 2x AGNNConv(D=320) -> marker weight -> BN+LeakyReLU ->
// softmax @ ref_center -> 2x AGNNConv(D=16) -> row softmax.
// N=50000, E=300000 (incl. self-loops => every dst segment non-empty).
//
// R2 design: one fully-fused wave-per-node conv kernel (scores + segment
// softmax + weighted aggregation), CSR built once, no atomics in convs.

#define D_BIG 320
#define D_SMALL 16

__global__ void fill_u32(unsigned* p, unsigned v, int n) {
    int i = blockIdx.x * blockDim.x + threadIdx.x;
    if (i < n) p[i] = v;
}

// ---------------- CSR build (dst-major) ----------------
__global__ void count_deg(const int* __restrict__ dst, unsigned* __restrict__ deg, int nE) {
    int k = blockIdx.x * blockDim.x + threadIdx.x;
    if (k < nE) atomicAdd(&deg[dst[k]], 1u);
}

__global__ void prefix_sum(const unsigned* __restrict__ deg, unsigned* __restrict__ rowstart, int n) {
    __shared__ unsigned buf[1024];
    __shared__ unsigned carry;
    if (threadIdx.x == 0) carry = 0u;
    __syncthreads();
    for (int base = 0; base < n; base += 1024) {
        int i = base + (int)threadIdx.x;
        unsigned v = (i < n) ? deg[i] : 0u;
        buf[threadIdx.x] = v;
        __syncthreads();
        for (int off = 1; off < 1024; off <<= 1) {
            unsigned t = (threadIdx.x >= (unsigned)off) ? buf[threadIdx.x - off] : 0u;
            __syncthreads();
            buf[threadIdx.x] += t;
            __syncthreads();
        }
        unsigned incl  = buf[threadIdx.x];
        unsigned cbase = carry;
        if (i < n) rowstart[i] = cbase + incl - v;
        __syncthreads();
        if (threadIdx.x == 0) carry = cbase + buf[1023];
        __syncthreads();
    }
    if (threadIdx.x == 0) rowstart[n] = carry;
}

__global__ void scatter_edges(const int* __restrict__ src, const int* __restrict__ dst,
                              const unsigned* __restrict__ rowstart, unsigned* __restrict__ cursor,
                              int* __restrict__ esrc, int nE) {
    int k = blockIdx.x * blockDim.x + threadIdx.x;
    if (k >= nE) return;
    int t = dst[k];
    unsigned pos = rowstart[t] + atomicAdd(&cursor[t], 1u);
    esrc[pos] = src[k];
}

// ---------------- fully fused AGNNConv: wave per dst node ----------------
// EPI: 0 = plain store, 1 = marker-weight + f_pre epilogue (D=320),
//      2 = row softmax(acc * inv_temp) epilogue (D=16)
template <int D, int EPI>
__global__ void agnn_fused(const float* __restrict__ h,
                           const unsigned* __restrict__ rowstart,
                           const int* __restrict__ esrc,
                           const float* __restrict__ beta,
                           const float* __restrict__ mw,     // EPI==1 only
                           float* __restrict__ out,
                           float* __restrict__ f_out,        // EPI==1 only
                           float inv_temp,                   // EPI==2 only
                           int n) {
    constexpr int U = (D + 63) / 64;
    constexpr int CAP = 512;                   // max degree supported (actual max ~25)
    __shared__ float ws[4][CAP];
    int wslot = threadIdx.x >> 6;
    int i     = (blockIdx.x * blockDim.x + threadIdx.x) >> 6;
    int lane  = threadIdx.x & 63;
    if (i >= n) return;

    unsigned r0 = rowstart[i], r1 = rowstart[i + 1];
    unsigned deg = r1 - r0;
    float b0 = beta[0];

    // dst row -> registers, norm inline
    const float* pd = h + (size_t)i * D;
    float dr[U];
    float nt2 = 0.f;
    #pragma unroll
    for (int u = 0; u < U; u++) {
        int d = lane + 64 * u;
        float v = (d < D) ? pd[d] : 0.f;
        dr[u] = v;
        nt2 += v * v;
    }
    #pragma unroll
    for (int m = 32; m >= 1; m >>= 1) nt2 += __shfl_xor(nt2, m);
    float nt = fmaxf(sqrtf(nt2), 1e-12f);

    // ---- phase 1: per-edge cosine scores -> LDS ----
    for (unsigned base = r0; base < r1; base += 64) {
        unsigned j = base + (unsigned)lane;
        int sv = (j < r1) ? esrc[j] : 0;
        int cnt = (int)((r1 - base) > 64u ? 64u : (r1 - base));
        for (int t = 0; t < cnt; t++) {
            int s = __shfl(sv, t);
            const float* pr = h + (size_t)s * D;
            float dot = 0.f, ss2 = 0.f;
            #pragma unroll
            for (int u = 0; u < U; u++) {
                int d = lane + 64 * u;
                if (d < D) { float v = pr[d]; dot += v * dr[u]; ss2 += v * v; }
            }
            #pragma unroll
            for (int m = 32; m >= 1; m >>= 1) {
                dot += __shfl_xor(dot, m);
                ss2 += __shfl_xor(ss2, m);
            }
            float ns = fmaxf(sqrtf(ss2), 1e-12f);
            float sc = b0 * dot / (ns * nt);     // temp = 1.0 for all convs
            unsigned idx = base + (unsigned)t - r0;
            if (lane == 0 && idx < CAP) ws[wslot][idx] = sc;
        }
    }

    // ---- phase 2: in-wave segment softmax over ws[0..deg) ----
    float mx = -1e30f;
    for (unsigned k = lane; k < deg; k += 64) mx = fmaxf(mx, ws[wslot][k]);
    #pragma unroll
    for (int m = 32; m >= 1; m >>= 1) mx = fmaxf(mx, __shfl_xor(mx, m));
    float l = 0.f;
    for (unsigned k = lane; k < deg; k += 64) {
        float t = expf(ws[wslot][k] - mx);
        ws[wslot][k] = t;
        l += t;
    }
    #pragma unroll
    for (int m = 32; m >= 1; m >>= 1) l += __shfl_xor(l, m);
    float inv = 1.f / l;

    // ---- phase 3: weighted aggregation (src rows re-read, L2-hot) ----
    float acc[U];
    #pragma unroll
    for (int u = 0; u < U; u++) acc[u] = 0.f;
    for (unsigned base = r0; base < r1; base += 64) {
        unsigned j = base + (unsigned)lane;
        int   sv = (j < r1) ? esrc[j] : 0;
        float wv = (j < r1) ? ws[wslot][j - r0] : 0.f;
        int cnt = (int)((r1 - base) > 64u ? 64u : (r1 - base));
        for (int t = 0; t < cnt; t++) {
            int   s = __shfl(sv, t);
            float a = __shfl(wv, t) * inv;
            const float* pr = h + (size_t)s * D;
            #pragma unroll
            for (int u = 0; u < U; u++) {
                int d = lane + 64 * u;
                if (d < D) acc[u] += a * pr[d];
            }
        }
    }

    // ---- epilogue ----
    if (EPI == 0) {
        #pragma unroll
        for (int u = 0; u < U; u++) {
            int d = lane + 64 * u;
            if (d < D) out[(size_t)i * D + d] = acc[u];
        }
    } else if (EPI == 1) {
        // marker weight in-register, store fea, reduce f_pre (c = lane & 15)
        float fsum = 0.f;
        #pragma unroll
        for (int u = 0; u < U; u++) {
            int d = lane + 64 * u;
            float v = acc[u] * mw[d];
            out[(size_t)i * D + d] = v;
            fsum += v;
        }
        fsum += __shfl_xor(fsum, 16);
        fsum += __shfl_xor(fsum, 32);
        if (lane < 16) f_out[(size_t)i * 16 + lane] = fsum;
    } else {
        // D == 16: row softmax of acc * inv_temp across lanes 0..15
        float v = acc[0] * inv_temp;
        float m2 = v;
        #pragma unroll
        for (int mm = 8; mm >= 1; mm >>= 1) m2 = fmaxf(m2, __shfl_xor(m2, mm));
        float ee = expf(v - m2);
        float ssum = ee;
        #pragma unroll
        for (int mm = 8; mm >= 1; mm >>= 1) ssum += __shfl_xor(ssum, mm);
        if (lane < 16) out[(size_t)i * 16 + lane] = ee / ssum;
    }
}

// ---------------- BatchNorm stats ----------------
__global__ void bn_reduce(const float* __restrict__ f, float* __restrict__ stats, int n) {
    int c = threadIdx.x & 15;
    int g = threadIdx.x >> 4;
    float s = 0.f, s2 = 0.f;
    for (int i = blockIdx.x * 16 + g; i < n; i += gridDim.x * 16) {
        float v = f[(size_t)i * 16 + c];
        s += v; s2 += v * v;
    }
    __shared__ float ls[256], ls2[256];
    ls[threadIdx.x] = s; ls2[threadIdx.x] = s2;
    __syncthreads();
    for (int off = 128; off >= 16; off >>= 1) {
        if ((int)threadIdx.x < off) {
            ls[threadIdx.x]  += ls[threadIdx.x + off];
            ls2[threadIdx.x] += ls2[threadIdx.x + off];
        }
        __syncthreads();
    }
    if (threadIdx.x < 16) {
        atomicAdd(&stats[threadIdx.x], ls[threadIdx.x]);
        atomicAdd(&stats[16 + threadIdx.x], ls2[threadIdx.x]);
    }
}

__global__ void bn_finalize(float* __restrict__ stats, const float* __restrict__ w,
                            const float* __restrict__ b, int n) {
    int c = threadIdx.x;
    if (c < 16) {
        float mean  = stats[c] / (float)n;
        float var   = fmaxf(stats[16 + c] / (float)n - mean * mean, 0.f);
        float scale = w[c] / sqrtf(var + 1e-5f);
        stats[32 + c] = scale;
        stats[48 + c] = b[c] - mean * scale;
    }
}

// ---------------- BN apply + LeakyReLU + softmax(f/T3) @ ref_center ----------------
__global__ void bn_apply_p(float* __restrict__ f, const float* __restrict__ stats,
                           const float* __restrict__ rc, float* __restrict__ p, int n) {
    __shared__ float s_rc[16 * D_BIG];   // 20 KB
    __shared__ float s_sc[16], s_sh[16];
    for (int idx = threadIdx.x; idx < 16 * D_BIG; idx += blockDim.x) s_rc[idx] = rc[idx];
    if (threadIdx.x < 16) { s_sc[threadIdx.x] = stats[32 + threadIdx.x]; s_sh[threadIdx.x] = stats[48 + threadIdx.x]; }
    __syncthreads();

    int wave = (blockIdx.x * blockDim.x + threadIdx.x) >> 6;
    int nw   = (gridDim.x * blockDim.x) >> 6;
    int lane = threadIdx.x & 63;

    for (int i = wave; i < n; i += nw) {
        const float* fr = f + (size_t)i * 16;
        float fv[16];
        float mx = -1e30f;
        #pragma unroll
        for (int c = 0; c < 16; c++) {
            float v = fmaf(fr[c], s_sc[c], s_sh[c]);
            v = (v >= 0.f) ? v : 0.25f * v;           // LeakyReLU(0.25)
            fv[c] = v;
            mx = fmaxf(mx, v);
        }
        if (lane < 16) f[(size_t)i * 16 + lane] = fv[lane];   // lockstep: loads precede stores

        float sp[16]; float sum = 0.f;
        #pragma unroll
        for (int c = 0; c < 16; c++) { float t = expf((fv[c] - mx) * 10.0f); sp[c] = t; sum += t; }
        float isum = 1.f / sum;

        #pragma unroll
        for (int u = 0; u < 5; u++) {
            int d = lane + 64 * u;
            float acc = 0.f;
            #pragma unroll
            for (int c = 0; c < 16; c++) acc += sp[c] * s_rc[c * D_BIG + d];
            p[(size_t)i * D_BIG + d] = acc * isum;
        }
    }
}

extern "C" void kernel_launch(void* const* d_in, const int* in_sizes, int n_in,
                              void* d_out, int out_size, void* d_ws, size_t ws_size,
                              hipStream_t stream) {
    const float* x    = (const float*)d_in[0];
    const int*   src  = (const int*)d_in[1];
    const int*   dst  = (const int*)d_in[2];
    const float* mw   = (const float*)d_in[3];
    const float* bnw  = (const float*)d_in[4];
    const float* bnb  = (const float*)d_in[5];
    const float* rc   = (const float*)d_in[6];
    const float* beta = (const float*)d_in[7];

    const int n  = in_sizes[0] / D_BIG;   // 50000
    const int nE = in_sizes[1];           // 300000

    float* out     = (float*)d_out;
    float* fea_out = out;                          // N*320
    float* f_out   = out + (size_t)n * D_BIG;      // N*16
    float* p_out   = f_out + (size_t)n * 16;       // N*320
    float* o_out   = p_out + (size_t)n * D_BIG;    // N*16

    // workspace carve (~5 MB)
    char* w = (char*)d_ws;
    auto carve = [&](size_t bytes) { void* r = (void*)w; w += (bytes + 255) & ~(size_t)255; return r; };
    unsigned* deg      = (unsigned*)carve((size_t)n * 4);
    unsigned* rowstart = (unsigned*)carve((size_t)(n + 1) * 4);
    unsigned* cursor   = (unsigned*)carve((size_t)n * 4);
    int*      esrc     = (int*)carve((size_t)nE * 4);
    float*    stats    = (float*)carve(64 * 4);
    float*    t16      = (float*)carve((size_t)n * 16 * 4);
    float*    h1       = p_out;  // p region doubles as conv1 output until bn_apply_p

    const int TB = 256;
    auto cdiv = [](int a, int b) { return (a + b - 1) / b; };

    // CSR build (once; reused by all 4 convs)
    fill_u32<<<cdiv(n, TB), TB, 0, stream>>>(deg, 0u, n);
    count_deg<<<cdiv(nE, TB), TB, 0, stream>>>(dst, deg, nE);
    prefix_sum<<<1, 1024, 0, stream>>>(deg, rowstart, n);
    fill_u32<<<cdiv(n, TB), TB, 0, stream>>>(cursor, 0u, n);
    scatter_edges<<<cdiv(nE, TB), TB, 0, stream>>>(src, dst, rowstart, cursor, esrc, nE);

    // conv1: x -> h1 (p region)
    agnn_fused<D_BIG, 0><<<cdiv(n, 4), TB, 0, stream>>>(x, rowstart, esrc, beta,
                                                        nullptr, h1, nullptr, 0.f, n);
    // conv2 + marker + f_pre: h1 -> fea_out, f_out
    agnn_fused<D_BIG, 1><<<cdiv(n, 4), TB, 0, stream>>>(h1, rowstart, esrc, beta,
                                                        mw, fea_out, f_out, 0.f, n);
    // BatchNorm (training-mode batch stats)
    fill_u32<<<1, 64, 0, stream>>>((unsigned*)stats, 0u, 64);
    bn_reduce<<<128, TB, 0, stream>>>(f_out, stats, n);
    bn_finalize<<<1, 16, 0, stream>>>(stats, bnw, bnb, n);
    // BN apply + LeakyReLU (f in place) + p = softmax(f*10) @ rc (overwrites h1)
    bn_apply_p<<<1024, TB, 0, stream>>>(f_out, stats, rc, p_out, n);
    // conv3: f -> t16
    agnn_fused<D_SMALL, 0><<<cdiv(n, 4), TB, 0, stream>>>(f_out, rowstart, esrc, beta,
                                                          nullptr, t16, nullptr, 0.f, n);
    // conv4 + softmax(/T2): t16 -> o_out
    agnn_fused<D_SMALL, 2><<<cdiv(n, 4), TB, 0, stream>>>(t16, rowstart, esrc, beta,
                                                          nullptr, o_out, nullptr, 0.2f, n);
}

// Round 3
// 498.607 us; speedup vs baseline: 1.8549x; 1.4426x over previous
//
#include <hip/hip_runtime.h>
#include <cstdint>
#include <cstddef>

// GCNClassifier: 2x AGNNConv(D=320) -> marker weight -> BN+LeakyReLU ->
// softmax @ ref_center -> 2x AGNNConv(D=16) -> row softmax.
// N=50000, E=300000 (incl. self-loops => every dst segment non-empty).
//
// R3: online-softmax single-pass conv (each src row read once, used for both
// cosine score and weighted accumulate), float4 row I/O, 3-kernel scan.

#define D_BIG 320

__device__ __forceinline__ float dot4(float4 a, float4 b) {
    return a.x * b.x + a.y * b.y + a.z * b.z + a.w * b.w;
}

__global__ void fill_u32(unsigned* p, unsigned v, int n) {
    int i = blockIdx.x * blockDim.x + threadIdx.x;
    if (i < n) p[i] = v;
}

// ---------------- CSR build (dst-major) ----------------
__global__ void count_deg(const int* __restrict__ dst, unsigned* __restrict__ deg, int nE) {
    int k = blockIdx.x * blockDim.x + threadIdx.x;
    if (k < nE) atomicAdd(&deg[dst[k]], 1u);
}

// Two-level scan: block-local exclusive scan + block sums
__global__ void scan1(const unsigned* __restrict__ deg, unsigned* __restrict__ rs,
                      unsigned* __restrict__ bsum, int n) {
    __shared__ unsigned buf[256];
    int i = blockIdx.x * 256 + threadIdx.x;
    unsigned v = (i < n) ? deg[i] : 0u;
    buf[threadIdx.x] = v;
    __syncthreads();
    for (int off = 1; off < 256; off <<= 1) {
        unsigned t = (threadIdx.x >= (unsigned)off) ? buf[threadIdx.x - off] : 0u;
        __syncthreads();
        buf[threadIdx.x] += t;
        __syncthreads();
    }
    if (i < n) rs[i] = buf[threadIdx.x] - v;           // exclusive
    if (threadIdx.x == 255) bsum[blockIdx.x] = buf[255];
}

__global__ void scan2(unsigned* __restrict__ bsum, int nb) {   // nb <= 256
    __shared__ unsigned buf[256];
    unsigned v = ((int)threadIdx.x < nb) ? bsum[threadIdx.x] : 0u;
    buf[threadIdx.x] = v;
    __syncthreads();
    for (int off = 1; off < 256; off <<= 1) {
        unsigned t = (threadIdx.x >= (unsigned)off) ? buf[threadIdx.x - off] : 0u;
        __syncthreads();
        buf[threadIdx.x] += t;
        __syncthreads();
    }
    if ((int)threadIdx.x < nb) bsum[threadIdx.x] = buf[threadIdx.x] - v;   // exclusive
}

__global__ void scan3(unsigned* __restrict__ rs, const unsigned* __restrict__ bsum,
                      unsigned* __restrict__ cursor, float* __restrict__ stats,
                      int n, int nE) {
    int i = blockIdx.x * 256 + threadIdx.x;
    if (i < n) { rs[i] += bsum[blockIdx.x]; cursor[i] = 0u; }
    if (i == 0) rs[n] = (unsigned)nE;
    if (blockIdx.x == 0 && threadIdx.x < 64) stats[threadIdx.x] = 0.f;
}

__global__ void scatter_edges(const int* __restrict__ src, const int* __restrict__ dst,
                              const unsigned* __restrict__ rowstart, unsigned* __restrict__ cursor,
                              int* __restrict__ esrc, int nE) {
    int k = blockIdx.x * blockDim.x + threadIdx.x;
    if (k >= nE) return;
    int t = dst[k];
    unsigned pos = rowstart[t] + atomicAdd(&cursor[t], 1u);
    esrc[pos] = src[k];
}

// ---------------- fused AGNNConv D=320, online softmax, wave per node -------
// EPI: 0 = plain store, 1 = marker-weight + f_pre epilogue
template <int EPI>
__global__ void agnn_big(const float* __restrict__ h,
                         const unsigned* __restrict__ rowstart,
                         const int* __restrict__ esrc,
                         const float* __restrict__ beta,
                         const float* __restrict__ mw,     // EPI==1 only
                         float* __restrict__ out,
                         float* __restrict__ f_out,        // EPI==1 only
                         int n) {
    int i    = (blockIdx.x * blockDim.x + threadIdx.x) >> 6;
    int lane = threadIdx.x & 63;
    if (i >= n) return;
    unsigned r0 = rowstart[i], r1 = rowstart[i + 1];
    float b0 = beta[0];
    bool lo = lane < 16;

    // dst row -> registers (row = 80 float4: 64 on all lanes + 16 on lanes<16)
    const float4* pd = (const float4*)(h + (size_t)i * D_BIG);
    float4 d0 = pd[lane];
    float4 d1 = lo ? pd[64 + lane] : float4{0.f, 0.f, 0.f, 0.f};
    float nt2 = dot4(d0, d0) + dot4(d1, d1);
    #pragma unroll
    for (int m = 32; m >= 1; m >>= 1) nt2 += __shfl_xor(nt2, m);
    float nt = fmaxf(sqrtf(nt2), 1e-12f);

    float4 a0 = {0.f, 0.f, 0.f, 0.f}, a1 = {0.f, 0.f, 0.f, 0.f};
    float mrun = -1e30f, lrun = 0.f;

    for (unsigned base = r0; base < r1; base += 64) {
        unsigned j = base + (unsigned)lane;
        int sv = (j < r1) ? esrc[j] : 0;
        int cnt = (int)min(r1 - base, 64u);
        for (int t = 0; t < cnt; t++) {
            int s = __shfl(sv, t);
            const float4* ps = (const float4*)(h + (size_t)s * D_BIG);
            float4 r0v = ps[lane];
            float4 r1v = lo ? ps[64 + lane] : float4{0.f, 0.f, 0.f, 0.f};
            float dt = dot4(r0v, d0) + dot4(r1v, d1);
            float s2 = dot4(r0v, r0v) + dot4(r1v, r1v);
            #pragma unroll
            for (int m = 32; m >= 1; m >>= 1) {
                dt += __shfl_xor(dt, m);
                s2 += __shfl_xor(s2, m);
            }
            float sc = b0 * dt / (fmaxf(sqrtf(s2), 1e-12f) * nt);  // temp = 1.0
            float mn = fmaxf(mrun, sc);
            float alpha = __expf(mrun - mn);
            float w = __expf(sc - mn);
            mrun = mn;
            lrun = lrun * alpha + w;
            a0.x = a0.x * alpha + w * r0v.x;  a0.y = a0.y * alpha + w * r0v.y;
            a0.z = a0.z * alpha + w * r0v.z;  a0.w = a0.w * alpha + w * r0v.w;
            a1.x = a1.x * alpha + w * r1v.x;  a1.y = a1.y * alpha + w * r1v.y;
            a1.z = a1.z * alpha + w * r1v.z;  a1.w = a1.w * alpha + w * r1v.w;
        }
    }
    float inv = 1.f / lrun;
    a0.x *= inv; a0.y *= inv; a0.z *= inv; a0.w *= inv;
    a1.x *= inv; a1.y *= inv; a1.z *= inv; a1.w *= inv;

    if (EPI == 0) {
        float4* po = (float4*)(out + (size_t)i * D_BIG);
        po[lane] = a0;
        if (lo) po[64 + lane] = a1;
    } else {
        const float4* pmw = (const float4*)mw;
        float4 w0 = pmw[lane];
        float4 w1 = lo ? pmw[64 + lane] : float4{0.f, 0.f, 0.f, 0.f};
        float4 v0 = {a0.x * w0.x, a0.y * w0.y, a0.z * w0.z, a0.w * w0.w};
        float4 v1 = {a1.x * w1.x, a1.y * w1.y, a1.z * w1.z, a1.w * w1.w};
        float4* po = (float4*)(out + (size_t)i * D_BIG);
        po[lane] = v0;
        if (lo) po[64 + lane] = v1;
        // f_pre: channel c = d & 15; lane L, element q -> c = (4L+q)&15.
        // lanes with equal L%4 share the channel mapping -> xor-reduce 4,8,16,32.
        float fs[4] = {v0.x + v1.x, v0.y + v1.y, v0.z + v1.z, v0.w + v1.w};
        #pragma unroll
        for (int mask = 4; mask <= 32; mask <<= 1) {
            #pragma unroll
            for (int q = 0; q < 4; q++) fs[q] += __shfl_xor(fs[q], mask);
        }
        if (lane < 4) {
            float4* pf = (float4*)(f_out + (size_t)i * 16);
            pf[lane] = float4{fs[0], fs[1], fs[2], fs[3]};
        }
    }
}

// ---------------- fused AGNNConv D=16, online softmax, wave per node --------
// EPI: 0 = plain store, 2 = row softmax(acc * inv_temp)
template <int EPI>
__global__ void agnn_small(const float* __restrict__ h,
                           const unsigned* __restrict__ rowstart,
                           const int* __restrict__ esrc,
                           const float* __restrict__ beta,
                           float* __restrict__ out,
                           float inv_temp,
                           int n) {
    int i    = (blockIdx.x * blockDim.x + threadIdx.x) >> 6;
    int lane = threadIdx.x & 63;
    if (i >= n) return;
    unsigned r0 = rowstart[i], r1 = rowstart[i + 1];
    float b0 = beta[0];
    bool act = lane < 16;

    float dv = act ? h[(size_t)i * 16 + lane] : 0.f;
    float nt2 = dv * dv;
    #pragma unroll
    for (int m = 8; m >= 1; m >>= 1) nt2 += __shfl_xor(nt2, m);
    float nt = fmaxf(sqrtf(nt2), 1e-12f);

    float acc = 0.f, mrun = -1e30f, lrun = 0.f;
    for (unsigned base = r0; base < r1; base += 64) {
        unsigned j = base + (unsigned)lane;
        int sv = (j < r1) ? esrc[j] : 0;
        int cnt = (int)min(r1 - base, 64u);
        for (int t = 0; t < cnt; t++) {
            int s = __shfl(sv, t);
            float rv = act ? h[(size_t)s * 16 + lane] : 0.f;
            float dt = rv * dv, s2 = rv * rv;
            #pragma unroll
            for (int m = 8; m >= 1; m >>= 1) {
                dt += __shfl_xor(dt, m);
                s2 += __shfl_xor(s2, m);
            }
            float sc = b0 * dt / (fmaxf(sqrtf(s2), 1e-12f) * nt);
            float mn = fmaxf(mrun, sc);
            float alpha = __expf(mrun - mn);
            float w = __expf(sc - mn);
            mrun = mn;
            lrun = lrun * alpha + w;
            acc = acc * alpha + w * rv;
        }
    }
    float val = acc / lrun;

    if (EPI == 0) {
        if (act) out[(size_t)i * 16 + lane] = val;
    } else {
        float v = val * inv_temp;
        float m2 = v;
        #pragma unroll
        for (int mm = 8; mm >= 1; mm >>= 1) m2 = fmaxf(m2, __shfl_xor(m2, mm));
        float ee = __expf(v - m2);
        float ssum = ee;
        #pragma unroll
        for (int mm = 8; mm >= 1; mm >>= 1) ssum += __shfl_xor(ssum, mm);
        if (act) out[(size_t)i * 16 + lane] = ee / ssum;
    }
}

// ---------------- BatchNorm stats ----------------
__global__ void bn_reduce(const float* __restrict__ f, float* __restrict__ stats, int n) {
    int c = threadIdx.x & 15;
    int g = threadIdx.x >> 4;
    float s = 0.f, s2 = 0.f;
    for (int i = blockIdx.x * 16 + g; i < n; i += gridDim.x * 16) {
        float v = f[(size_t)i * 16 + c];
        s += v; s2 += v * v;
    }
    __shared__ float ls[256], ls2[256];
    ls[threadIdx.x] = s; ls2[threadIdx.x] = s2;
    __syncthreads();
    for (int off = 128; off >= 16; off >>= 1) {
        if ((int)threadIdx.x < off) {
            ls[threadIdx.x]  += ls[threadIdx.x + off];
            ls2[threadIdx.x] += ls2[threadIdx.x + off];
        }
        __syncthreads();
    }
    if (threadIdx.x < 16) {
        atomicAdd(&stats[threadIdx.x], ls[threadIdx.x]);
        atomicAdd(&stats[16 + threadIdx.x], ls2[threadIdx.x]);
    }
}

__global__ void bn_finalize(float* __restrict__ stats, const float* __restrict__ w,
                            const float* __restrict__ b, int n) {
    int c = threadIdx.x;
    if (c < 16) {
        float mean  = stats[c] / (float)n;
        float var   = fmaxf(stats[16 + c] / (float)n - mean * mean, 0.f);
        float scale = w[c] / sqrtf(var + 1e-5f);
        stats[32 + c] = scale;
        stats[48 + c] = b[c] - mean * scale;
    }
}

// ---------------- BN apply + LeakyReLU + softmax(f*10) @ ref_center ----------
__global__ void bn_apply_p(float* __restrict__ f, const float* __restrict__ stats,
                           const float* __restrict__ rc, float* __restrict__ p, int n) {
    __shared__ float s_rc[16 * D_BIG];   // 20 KB
    __shared__ float s_sc[16], s_sh[16];
    for (int idx = threadIdx.x; idx < 16 * D_BIG; idx += blockDim.x) s_rc[idx] = rc[idx];
    if (threadIdx.x < 16) { s_sc[threadIdx.x] = stats[32 + threadIdx.x]; s_sh[threadIdx.x] = stats[48 + threadIdx.x]; }
    __syncthreads();

    int wave = (blockIdx.x * blockDim.x + threadIdx.x) >> 6;
    int nw   = (gridDim.x * blockDim.x) >> 6;
    int lane = threadIdx.x & 63;

    for (int i = wave; i < n; i += nw) {
        const float* fr = f + (size_t)i * 16;
        float fv[16];
        float mx = -1e30f;
        #pragma unroll
        for (int c = 0; c < 16; c++) {
            float v = fmaf(fr[c], s_sc[c], s_sh[c]);
            v = (v >= 0.f) ? v : 0.25f * v;           // LeakyReLU(0.25)
            fv[c] = v;
            mx = fmaxf(mx, v);
        }
        if (lane < 16) f[(size_t)i * 16 + lane] = fv[lane];   // lockstep: loads precede stores

        float sp[16]; float sum = 0.f;
        #pragma unroll
        for (int c = 0; c < 16; c++) { float t = __expf((fv[c] - mx) * 10.0f); sp[c] = t; sum += t; }
        float isum = 1.f / sum;

        #pragma unroll
        for (int u = 0; u < 5; u++) {
            int d = lane + 64 * u;
            float acc = 0.f;
            #pragma unroll
            for (int c = 0; c < 16; c++) acc += sp[c] * s_rc[c * D_BIG + d];
            p[(size_t)i * D_BIG + d] = acc * isum;
        }
    }
}

extern "C" void kernel_launch(void* const* d_in, const int* in_sizes, int n_in,
                              void* d_out, int out_size, void* d_ws, size_t ws_size,
                              hipStream_t stream) {
    const float* x    = (const float*)d_in[0];
    const int*   src  = (const int*)d_in[1];
    const int*   dst  = (const int*)d_in[2];
    const float* mw   = (const float*)d_in[3];
    const float* bnw  = (const float*)d_in[4];
    const float* bnb  = (const float*)d_in[5];
    const float* rc   = (const float*)d_in[6];
    const float* beta = (const float*)d_in[7];

    const int n  = in_sizes[0] / D_BIG;   // 50000
    const int nE = in_sizes[1];           // 300000

    float* out     = (float*)d_out;
    float* fea_out = out;                          // N*320
    float* f_out   = out + (size_t)n * D_BIG;      // N*16
    float* p_out   = f_out + (size_t)n * 16;       // N*320
    float* o_out   = p_out + (size_t)n * D_BIG;    // N*16

    // workspace carve (~5 MB)
    char* w = (char*)d_ws;
    auto carve = [&](size_t bytes) { void* r = (void*)w; w += (bytes + 255) & ~(size_t)255; return r; };
    unsigned* deg      = (unsigned*)carve((size_t)n * 4);
    unsigned* rowstart = (unsigned*)carve((size_t)(n + 1) * 4);
    unsigned* cursor   = (unsigned*)carve((size_t)n * 4);
    unsigned* bsum     = (unsigned*)carve(256 * 4);
    int*      esrc     = (int*)carve((size_t)nE * 4);
    float*    stats    = (float*)carve(64 * 4);
    float*    t16      = (float*)carve((size_t)n * 16 * 4);
    float*    h1       = p_out;  // p region doubles as conv1 output until bn_apply_p

    const int TB = 256;
    auto cdiv = [](int a, int b) { return (a + b - 1) / b; };
    const int nb = cdiv(n, 256);   // 196 (<=256 required by scan2)

    // CSR build (once; reused by all 4 convs)
    fill_u32<<<cdiv(n, TB), TB, 0, stream>>>(deg, 0u, n);
    count_deg<<<cdiv(nE, TB), TB, 0, stream>>>(dst, deg, nE);
    scan1<<<nb, 256, 0, stream>>>(deg, rowstart, bsum, n);
    scan2<<<1, 256, 0, stream>>>(bsum, nb);
    scan3<<<nb, 256, 0, stream>>>(rowstart, bsum, cursor, stats, n, nE);
    scatter_edges<<<cdiv(nE, TB), TB, 0, stream>>>(src, dst, rowstart, cursor, esrc, nE);

    // conv1: x -> h1 (p region)
    agnn_big<0><<<cdiv(n, 4), TB, 0, stream>>>(x, rowstart, esrc, beta, nullptr, h1, nullptr, n);
    // conv2 + marker + f_pre: h1 -> fea_out, f_out
    agnn_big<1><<<cdiv(n, 4), TB, 0, stream>>>(h1, rowstart, esrc, beta, mw, fea_out, f_out, n);
    // BatchNorm (training-mode batch stats)
    bn_reduce<<<128, TB, 0, stream>>>(f_out, stats, n);
    bn_finalize<<<1, 16, 0, stream>>>(stats, bnw, bnb, n);
    // BN apply + LeakyReLU (f in place) + p = softmax(f*10) @ rc (overwrites h1)
    bn_apply_p<<<512, TB, 0, stream>>>(f_out, stats, rc, p_out, n);
    // conv3: f -> t16
    agnn_small<0><<<cdiv(n, 4), TB, 0, stream>>>(f_out, rowstart, esrc, beta, t16, 0.f, n);
    // conv4 + softmax(/T2): t16 -> o_out
    agnn_small<2><<<cdiv(n, 4), TB, 0, stream>>>(t16, rowstart, esrc, beta, o_out, 0.2f, n);
}